// Round 1
// baseline (85.755 us; speedup 1.0000x reference)
//
#include <hip/hip_runtime.h>

// YoloV3 decoder: predictions (1, 145152, 85) fp32 ->
//   out0: bboxes   (145152, 4)  xyxy, /1536
//   out1: scores   (145152,)    objectness * max(class)
//   out2: class_pred (145152,)  argmax(class) as float value
//   out3: detections (145152, 6) {x,y,x2,y2, class_conf, class_pred}
// score_threshold input is unused by the reference.

#define N_ANCH 145152
#define NCH 85
#define NCLS 80

constexpr float INV_IMG = 1.0f / 1536.0f;
constexpr int APB = 128;   // anchors per block
constexpr int TPB = 128;   // threads per block (1 thread = 1 anchor in phase 2)

__global__ __launch_bounds__(TPB)
void yolo_decode(const float* __restrict__ pred, float* __restrict__ out) {
    // 128 anchors * 85 ch * 4 B = 43520 B LDS (fits static 64 KB; 3 blocks/CU)
    __shared__ float lds[APB * NCH];

    const int tid = threadIdx.x;
    const int blk = blockIdx.x;

    // ---- Phase 1: coalesced float4 staging of the block's contiguous region ----
    // block region = 128*85 floats = 43520 B, 16B-aligned for every block.
    const float4* __restrict__ src = (const float4*)(pred + (size_t)blk * (APB * NCH));
    float4* dst = (float4*)lds;
    constexpr int NVEC = APB * NCH / 4;  // 2720
    #pragma unroll 4
    for (int i = tid; i < NVEC; i += TPB) {
        dst[i] = src[i];
    }
    __syncthreads();

    // ---- Phase 2: one thread decodes one anchor from LDS ----
    // stride 85 floats between lanes -> bank = (21*lane + k) mod 32, all banks
    // covered per 32 lanes, 2-way aliasing per wave64 (free).
    const float* __restrict__ p = lds + tid * NCH;
    const float bx = p[0], by = p[1], bw = p[2], bh = p[3], obj = p[4];

    float cmax = p[5];
    int cidx = 0;
    #pragma unroll
    for (int k = 1; k < NCLS; ++k) {
        const float v = p[5 + k];
        if (v > cmax) { cmax = v; cidx = k; }   // strict > : first-max, matches jnp.argmax
    }

    const float cx = bx * INV_IMG;
    const float cy = by * INV_IMG;
    const float hw = bw * (INV_IMG * 0.5f);
    const float hh = bh * (INV_IMG * 0.5f);
    const float x0 = cx - hw, y0 = cy - hh;
    const float x1 = cx + hw, y1 = cy + hh;

    const int a = blk * APB + tid;
    const float score = obj * cmax;
    const float clsf = (float)cidx;

    // out0: bboxes, float4 aligned store
    ((float4*)out)[a] = make_float4(x0, y0, x1, y1);
    // out1: scores
    out[4 * N_ANCH + a] = score;
    // out2: class_pred (as float value)
    out[5 * N_ANCH + a] = clsf;
    // out3: detections, 6 floats per anchor, 24 B stride -> float2-aligned
    float2* det = (float2*)(out + 6 * (size_t)N_ANCH + (size_t)a * 6);
    det[0] = make_float2(x0, y0);
    det[1] = make_float2(x1, y1);
    det[2] = make_float2(cmax, clsf);
}

extern "C" void kernel_launch(void* const* d_in, const int* in_sizes, int n_in,
                              void* d_out, int out_size, void* d_ws, size_t ws_size,
                              hipStream_t stream) {
    const float* pred = (const float*)d_in[0];
    float* out = (float*)d_out;
    // 145152 / 128 = 1134 exactly, no tail handling needed
    yolo_decode<<<N_ANCH / APB, TPB, 0, stream>>>(pred, out);
}

// Round 2
// 83.393 us; speedup vs baseline: 1.0283x; 1.0283x over previous
//
#include <hip/hip_runtime.h>

// YoloV3 decoder: predictions (1, 145152, 85) fp32 ->
//   out0: bboxes     (145152, 4)  xyxy, /1536
//   out1: scores     (145152,)    objectness * max(class)
//   out2: class_pred (145152,)    argmax(class) as float value
//   out3: detections (145152, 6)  {x,y,x2,y2, class_conf, class_pred}
// score_threshold input is unused by the reference.
//
// Structure: 1 wave per block, 64 anchors per block.
//   Phase 1: HBM -> LDS via global_load_lds dwordx4 (no VGPR round trip).
//            Block region = 64*85 floats = 1360 float4 = 21.25 KB LDS
//            -> 7 blocks/CU resident (LDS-limited), 2268 blocks total.
//   Phase 2: thread a decodes anchor a from LDS (stride 85 floats = odd
//            -> all 32 banks covered, 2-way wave64 aliasing only = free).

#define N_ANCH 145152
#define NCH 85
#define NCLS 80

constexpr float INV_IMG = 1.0f / 1536.0f;
constexpr int APB = 64;    // anchors per block
constexpr int TPB = 64;    // one wave
constexpr int NVEC = APB * NCH / 4;        // 1360 float4 per block
constexpr int FULL_ITERS = NVEC / TPB;     // 21
constexpr int TAIL = NVEC - FULL_ITERS * TPB;  // 16

typedef const __attribute__((address_space(1))) void* gptr_t;
typedef __attribute__((address_space(3))) void* lptr_t;

__global__ __launch_bounds__(TPB)
void yolo_decode(const float* __restrict__ pred, float* __restrict__ out) {
    __shared__ float lds[APB * NCH];   // 21760 B

    const int lane = threadIdx.x;      // 0..63, single wave
    const int blk  = blockIdx.x;

    // ---- Phase 1: direct HBM -> LDS staging, 16 B per lane per issue ----
    const float4* __restrict__ gbase = (const float4*)(pred + (size_t)blk * (APB * NCH));
    float4* lbase = (float4*)lds;
    #pragma unroll
    for (int i = 0; i < FULL_ITERS; ++i) {
        __builtin_amdgcn_global_load_lds(
            (gptr_t)(gbase + i * TPB + lane),
            (lptr_t)(lbase + i * TPB + lane), 16, 0, 0);
    }
    if (lane < TAIL) {
        __builtin_amdgcn_global_load_lds(
            (gptr_t)(gbase + FULL_ITERS * TPB + lane),
            (lptr_t)(lbase + FULL_ITERS * TPB + lane), 16, 0, 0);
    }
    asm volatile("s_waitcnt vmcnt(0)" ::: "memory");
    __syncthreads();   // single-wave barrier: cheap, guarantees LDS visibility

    // ---- Phase 2: one thread decodes one anchor from LDS ----
    const float* __restrict__ p = lds + lane * NCH;
    const float bx = p[0], by = p[1], bw = p[2], bh = p[3], obj = p[4];

    float cmax = p[5];
    int cidx = 0;
    #pragma unroll
    for (int k = 1; k < NCLS; ++k) {
        const float v = p[5 + k];
        if (v > cmax) { cmax = v; cidx = k; }   // strict > : first-max, matches jnp.argmax
    }

    const float cx = bx * INV_IMG;
    const float cy = by * INV_IMG;
    const float hw = bw * (INV_IMG * 0.5f);
    const float hh = bh * (INV_IMG * 0.5f);
    const float x0 = cx - hw, y0 = cy - hh;
    const float x1 = cx + hw, y1 = cy + hh;

    const int a = blk * APB + lane;
    const float score = obj * cmax;
    const float clsf = (float)cidx;

    // out0: bboxes, float4 aligned coalesced store
    ((float4*)out)[a] = make_float4(x0, y0, x1, y1);
    // out1: scores
    out[4 * N_ANCH + a] = score;
    // out2: class_pred (as float value)
    out[5 * N_ANCH + a] = clsf;
    // out3: detections, 6 floats (24 B) per anchor, float2-aligned
    float2* det = (float2*)(out + 6 * (size_t)N_ANCH + (size_t)a * 6);
    det[0] = make_float2(x0, y0);
    det[1] = make_float2(x1, y1);
    det[2] = make_float2(cmax, clsf);
}

extern "C" void kernel_launch(void* const* d_in, const int* in_sizes, int n_in,
                              void* d_out, int out_size, void* d_ws, size_t ws_size,
                              hipStream_t stream) {
    const float* pred = (const float*)d_in[0];
    float* out = (float*)d_out;
    // 145152 / 64 = 2268 blocks exactly, no tail
    yolo_decode<<<N_ANCH / APB, TPB, 0, stream>>>(pred, out);
}